// Round 7
// baseline (339.197 us; speedup 1.0000x reference)
//
#include <hip/hip_runtime.h>
#include <math.h>

// ---------------- constants (shapes fixed by the reference) ----------------
#define IN_CH   256
#define HC      256   // H*C
#define H_HEADS 4
#define NEG_SLOPE 0.2f
#define LOG2E   1.44269504088896f
#define DEFER_THR 12.0f   // base-2 defer-max threshold (2^12 = 4096, fp32-safe)
#define MINIT   -3.0e38f  // finite "-inf" so pad edges (al=-INF) are exact no-ops

typedef __attribute__((ext_vector_type(8))) short short8;
typedef __attribute__((ext_vector_type(4))) short short4v;
typedef __attribute__((ext_vector_type(4))) float float4v;

// ---------------- helpers ----------------
__device__ __forceinline__ float bf2f(unsigned short b) {
    return __uint_as_float(((unsigned)b) << 16);
}
__device__ __forceinline__ unsigned short f2bf(float f) {
    unsigned u = __float_as_uint(f);
    u += 0x7fffu + ((u >> 16) & 1u);    // round-to-nearest-even
    return (unsigned short)(u >> 16);
}
__device__ __forceinline__ float lrelu(float a) {
    return a >= 0.f ? a : NEG_SLOPE * a;
}
// base-2 exp: single v_exp_f32 (natively 2^x on gfx950).
__device__ __forceinline__ float fexp2(float a) {
    return __builtin_amdgcn_exp2f(a);
}

// ---------------- kernels ----------------

// W (fp32, [256k x 256c] row-major) -> transposed bf16 (wt[c][k])
__global__ void prep_w(const float* __restrict__ w,
                       unsigned short* __restrict__ wt) {
    int idx = blockIdx.x * 256 + threadIdx.x;   // 65536 total
    int k = idx >> 8, c = idx & 255;
    wt[(size_t)c * 256 + k] = f2bf(w[idx]);
}

// xh = x @ W. Block = 16 rows x 256 cols (4 waves = 4 heads).
// Stages fp32 x directly; bf16 hi/lo split done in-register during staging.
// Epilogue fuses node_attn; att vectors pre-scaled by LOG2E so all logits
// live in base-2 domain (consumers use exp2).
__global__ __launch_bounds__(256) void gemm_xh(const float* __restrict__ x,
                                               const unsigned short* __restrict__ wt,
                                               const float* __restrict__ att_s,
                                               const float* __restrict__ att_d,
                                               unsigned short* __restrict__ xh_bf,
                                               float* __restrict__ a_src,
                                               float* __restrict__ a_dst, int N) {
    __shared__ __attribute__((aligned(16))) unsigned char lds_a[16384];
    int tid  = threadIdx.x;
    int wave = tid >> 6;            // == head index
    int lane = tid & 63;
    int quad = lane >> 4;
    int l16  = lane & 15;
    int rb   = blockIdx.x * 16;

    // ---- stage A-tile: 512 chunks x 8 floats -> hi/lo short8 slots ----
#pragma unroll
    for (int pass = 0; pass < 2; ++pass) {
        int s  = pass * 256 + tid;              // 0..511
        int kc = s >> 4;                        // 16-B chunk index (k/8)
        int m  = s & 15;                        // row within tile
        int grow = rb + m; if (grow >= N) grow = N - 1;
        const float* gp = x + (size_t)grow * IN_CH + kc * 8;
        float4v f0 = *(const float4v*)gp;
        float4v f1 = *(const float4v*)(gp + 4);
        short8 hi, lo;
#pragma unroll
        for (int j = 0; j < 4; ++j) {
            unsigned short h0 = f2bf(f0[j]);
            hi[j] = (short)h0;
            lo[j] = (short)f2bf(f0[j] - bf2f(h0));
            unsigned short h1 = f2bf(f1[j]);
            hi[4 + j] = (short)h1;
            lo[4 + j] = (short)f2bf(f1[j] - bf2f(h1));
        }
        *(short8*)(lds_a + (size_t)s * 16) = hi;
        *(short8*)(lds_a + 8192 + (size_t)s * 16) = lo;
    }
    __syncthreads();

    // ---- K-loop: 8 x { 2 ds_read_b128 + 4 x (1 B-load + 2 MFMA) } ----
    float4v acc[4] = {};
    const unsigned short* wt_base = wt + ((size_t)wave * 64 + l16) * IN_CH;
#pragma unroll
    for (int k0 = 0; k0 < 8; ++k0) {
        int kc   = k0 * 4 + quad;
        int slot = kc * 16 + l16;
        short8 a_hi = *(const short8*)(lds_a + slot * 16);
        short8 a_lo = *(const short8*)(lds_a + 8192 + slot * 16);
#pragma unroll
        for (int ct = 0; ct < 4; ++ct) {
            short8 bh = *(const short8*)(wt_base + (size_t)ct * 16 * IN_CH
                                         + k0 * 32 + quad * 8);
            acc[ct] = __builtin_amdgcn_mfma_f32_16x16x32_bf16(a_lo, bh, acc[ct], 0, 0, 0);
            acc[ct] = __builtin_amdgcn_mfma_f32_16x16x32_bf16(a_hi, bh, acc[ct], 0, 0, 0);
        }
    }

    // ---- epilogue: xh store + fused a_src/a_dst (head = wave, base-2) ----
    int cb = wave;
    float ps[4] = {0.f, 0.f, 0.f, 0.f};
    float pd[4] = {0.f, 0.f, 0.f, 0.f};
#pragma unroll
    for (int ct = 0; ct < 4; ++ct) {
        float as_c = att_s[cb * 64 + ct * 16 + l16] * LOG2E;
        float ad_c = att_d[cb * 64 + ct * 16 + l16] * LOG2E;
#pragma unroll
        for (int r = 0; r < 4; ++r) {
            float v = acc[ct][r];
            int grow = rb + quad * 4 + r;
            if (grow < N)
                xh_bf[(size_t)grow * HC + cb * 64 + ct * 16 + l16] = f2bf(v);
            ps[r] += v * as_c;
            pd[r] += v * ad_c;
        }
    }
#pragma unroll
    for (int off = 1; off < 16; off <<= 1) {
#pragma unroll
        for (int r = 0; r < 4; ++r) {
            ps[r] += __shfl_xor(ps[r], off);
            pd[r] += __shfl_xor(pd[r], off);
        }
    }
    if (l16 == 0) {
#pragma unroll
        for (int r = 0; r < 4; ++r) {
            int grow = rb + quad * 4 + r;
            if (grow < N) {
                a_src[(size_t)grow * 4 + cb] = ps[r];
                a_dst[(size_t)grow * 4 + cb] = pd[r];
            }
        }
    }
}

// degree histogram over dst
__global__ __launch_bounds__(256) void deg_count(const int* __restrict__ ei,
                                                 int* __restrict__ deg, int E) {
    int e = blockIdx.x * 256 + threadIdx.x;
    if (e >= E) return;
    atomicAdd(deg + ei[E + e], 1);
}

// ---- device-wide exclusive scan of deg[N] -> rowptr, cursor (2 phases) ----

// phase 1: per-block sums (1024 elements / block)
__global__ __launch_bounds__(256) void scan_part(const int* __restrict__ deg,
                                                 int* __restrict__ part, int N) {
    int t = threadIdx.x;
    int base = blockIdx.x * 1024 + t * 4;
    int s = 0;
    if (base + 4 <= N) {
        int4 v = *(const int4*)(deg + base);
        s = v.x + v.y + v.z + v.w;
    } else {
#pragma unroll
        for (int j = 0; j < 4; ++j)
            if (base + j < N) s += deg[base + j];
    }
#pragma unroll
    for (int off = 1; off < 64; off <<= 1) s += __shfl_xor(s, off);
    __shared__ int ws[4];
    if ((t & 63) == 0) ws[t >> 6] = s;
    __syncthreads();
    if (t == 0) part[blockIdx.x] = ws[0] + ws[1] + ws[2] + ws[3];
}

// phase 2: block offset = sum(part[0..bid)) computed in-block (NB ~ 49),
// then local exclusive scan, write rowptr & cursor.
__global__ __launch_bounds__(256) void scan_final(const int* __restrict__ deg,
                                                  const int* __restrict__ part,
                                                  int* __restrict__ rowptr,
                                                  int* __restrict__ cursor, int N) {
    __shared__ int sm[256];
    __shared__ int wsum[4];
    int t = threadIdx.x;
    int bacc = 0;
    for (int j = t; j < blockIdx.x; j += 256) bacc += part[j];
#pragma unroll
    for (int off = 1; off < 64; off <<= 1) bacc += __shfl_xor(bacc, off);
    if ((t & 63) == 0) wsum[t >> 6] = bacc;

    int base = blockIdx.x * 1024 + t * 4;
    int v0 = 0, v1 = 0, v2 = 0, v3 = 0;
    if (base + 4 <= N) {
        int4 v = *(const int4*)(deg + base);
        v0 = v.x; v1 = v.y; v2 = v.z; v3 = v.w;
    } else {
        if (base + 0 < N) v0 = deg[base + 0];
        if (base + 1 < N) v1 = deg[base + 1];
        if (base + 2 < N) v2 = deg[base + 2];
        if (base + 3 < N) v3 = deg[base + 3];
    }
    int s = v0 + v1 + v2 + v3;
    sm[t] = s;
    __syncthreads();
    for (int off = 1; off < 256; off <<= 1) {
        int tmp = (t >= off) ? sm[t - off] : 0;
        __syncthreads();
        sm[t] += tmp;
        __syncthreads();
    }
    int boff = wsum[0] + wsum[1] + wsum[2] + wsum[3];
    int run = boff + sm[t] - s;   // exclusive prefix for this thread
    int r0 = run, r1 = r0 + v0, r2 = r1 + v1, r3 = r2 + v2;
    if (base + 4 <= N) {
        *(int4*)(rowptr + base) = (int4){r0, r1, r2, r3};
        *(int4*)(cursor + base) = (int4){r0, r1, r2, r3};
    } else {
        if (base + 0 < N) { rowptr[base + 0] = r0; cursor[base + 0] = r0; }
        if (base + 1 < N) { rowptr[base + 1] = r1; cursor[base + 1] = r1; }
        if (base + 2 < N) { rowptr[base + 2] = r2; cursor[base + 2] = r2; }
        if (base + 3 < N) { rowptr[base + 3] = r3; cursor[base + 3] = r3; }
    }
}

// fill CSR + precompute per-edge logits (base-2, lrelu applied).
// csr_off holds PRE-SHIFTED byte offsets (src * 512); csr_al slot-ordered
// so gat_gather's reads are sequential.
__global__ __launch_bounds__(256) void fill_csr(const int* __restrict__ ei,
                                                const float* __restrict__ a_src,
                                                const float* __restrict__ a_dst,
                                                int* __restrict__ cursor,
                                                int* __restrict__ csr_off,
                                                float* __restrict__ csr_al, int E) {
    int e = blockIdx.x * 256 + threadIdx.x;
    if (e >= E) return;
    int s = ei[e], d = ei[E + e];
    float4v as = *(const float4v*)(a_src + (size_t)s * 4);
    float4v ad = *(const float4v*)(a_dst + (size_t)d * 4);
    float4v al;
#pragma unroll
    for (int h = 0; h < 4; ++h) al[h] = lrelu(as[h] + ad[h]);
    int slot = atomicAdd(cursor + d, 1);
    csr_off[slot] = s << 9;   // byte offset into xh_bf (HC*2 = 512 B/row)
    *(float4v*)(csr_al + (size_t)slot * 4) = al;
}

// TWO dsts per wave (lanes 0-31 -> d0, 32-63 -> d1), 8 channels/lane.
// DEPTH-2 software pipeline: rows for edges {i,i+1} AND {i+2,i+3} held in
// registers, loads for {i+4,i+5} issued at loop top -> 4 rows in flight
// per wave (was 2; kernel was latency-bound at VALUBusy 53%/HBM 42%).
// #pragma unroll 2 turns the stage-shift movs into SSA renames.
// Offsets clamp to [0, E-1] (memory-safe; pad contribution zeroed by
// al = -INF with finite m_init).
__global__ __launch_bounds__(256) void gat_gather(const int* __restrict__ csr_off,
                                                  const float* __restrict__ csr_al,
                                                  const int* __restrict__ rowptr,
                                                  const int* __restrict__ deg,
                                                  const unsigned short* __restrict__ xh_bf,
                                                  float* __restrict__ out,
                                                  float* __restrict__ pack,
                                                  int N, int E) {
    int wave = threadIdx.x >> 6, lane = threadIdx.x & 63;
    int half = lane >> 5;           // 0 -> d0, 1 -> d1
    int l32  = lane & 31;
    int h    = l32 >> 3;            // head (8 lanes per head)
    int d    = blockIdx.x * 8 + wave * 2 + half;
    bool dv  = d < N;
    int dc   = dv ? d : N - 1;
    int start = rowptr[dc];
    int cnt   = dv ? deg[dc] : 0;
    int cntMax = max(cnt, __shfl_xor(cnt, 32));
    int emax = E - 1;

    const char* xb = (const char*)xh_bf;
    int lboff = l32 * 16;

    float mE = MINIT, lE = 0.f, mO = MINIT, lO = 0.f;
    float accE[8] = {0.f, 0.f, 0.f, 0.f, 0.f, 0.f, 0.f, 0.f};
    float accO[8] = {0.f, 0.f, 0.f, 0.f, 0.f, 0.f, 0.f, 0.f};

#define LOFF(idx) (csr_off[min(start + (idx), emax)])
#define LAL(idx)  (((idx) < cnt) ? csr_al[(size_t)(start + (idx)) * 4 + h] : -INFINITY)

    // pipeline prologue: cur = edges {0,1}, nxt = edges {2,3}; offs for {4,5}
    int o4 = LOFF(4), o5 = LOFF(5);
    float alE  = LAL(0), alO  = LAL(1);
    float alE1 = LAL(2), alO1 = LAL(3);
    short8 xvE  = *(const short8*)(xb + (size_t)(unsigned)LOFF(0) + lboff);
    short8 xvO  = *(const short8*)(xb + (size_t)(unsigned)LOFF(1) + lboff);
    short8 xvE1 = *(const short8*)(xb + (size_t)(unsigned)LOFF(2) + lboff);
    short8 xvO1 = *(const short8*)(xb + (size_t)(unsigned)LOFF(3) + lboff);

#pragma unroll 2
    for (int i = 0; i < cntMax; i += 2) {
        // issue loads for edges {i+4,i+5}; fetch offsets for {i+6,i+7}
        short8 xvE2 = *(const short8*)(xb + (size_t)(unsigned)o4 + lboff);
        short8 xvO2 = *(const short8*)(xb + (size_t)(unsigned)o5 + lboff);
        int o6 = LOFF(i + 6), o7 = LOFF(i + 7);
        float alE2 = LAL(i + 4), alO2 = LAL(i + 5);

        bool ok = (alE <= mE + DEFER_THR) && (alO <= mO + DEFER_THR);
        if (__all(ok)) {
            // fast path: stale max, no rescale (pads: p = 0)
            float p = fexp2(alE - mE);
            float q = fexp2(alO - mO);
            lE += p; lO += q;
#pragma unroll
            for (int j = 0; j < 8; ++j) {
                accE[j] += p * bf2f((unsigned short)xvE[j]);
                accO[j] += q * bf2f((unsigned short)xvO[j]);
            }
        } else {
            // slow path: classic online-softmax rescale
            float mnE = fmaxf(mE, alE);
            float scE = fexp2(mE - mnE);
            float pE  = fexp2(alE - mnE);
            lE = lE * scE + pE;
            float mnO = fmaxf(mO, alO);
            float scO = fexp2(mO - mnO);
            float pO  = fexp2(alO - mnO);
            lO = lO * scO + pO;
#pragma unroll
            for (int j = 0; j < 8; ++j) {
                accE[j] = accE[j] * scE + pE * bf2f((unsigned short)xvE[j]);
                accO[j] = accO[j] * scO + pO * bf2f((unsigned short)xvO[j]);
            }
            mE = mnE; mO = mnO;
        }
        // stage shift (renamed away by unroll-2 + copy propagation)
        alE = alE1; alO = alO1; alE1 = alE2; alO1 = alO2;
        xvE = xvE1; xvO = xvO1; xvE1 = xvE2; xvO1 = xvO2;
        o4 = o6; o5 = o7;
    }
#undef LOFF
#undef LAL

    // merge E/O states (exact for stale maxes; cnt==0 -> l=0 -> o=0)
    float mm = fmaxf(mE, mO);
    float sE = fexp2(mE - mm), sO = fexp2(mO - mm);
    float l  = lE * sE + lO * sO;
    float inv = 1.f / (l + 1e-16f);
    if (dv) {
        float4v o0, o1;
#pragma unroll
        for (int j = 0; j < 4; ++j) {
            o0[j] = (accE[j] * sE + accO[j] * sO) * inv;
            o1[j] = (accE[4 + j] * sE + accO[4 + j] * sO) * inv;
        }
        float* orow = out + (size_t)d * HC + l32 * 8;
        *(float4v*)orow = o0;
        *(float4v*)(orow + 4) = o1;
        if ((l32 & 7) == 0) {
            pack[(size_t)d * 8 + h]     = mm;
            pack[(size_t)d * 8 + 4 + h] = inv;
        }
    }
}

// att[e,:] = exp2(lrelu(as+ad) - m2[d]) * inv_l[d].
// a_src/a_dst are 0.8 MB tables (L2-resident) -> random 16 B gathers are
// cheap here (edge-parallel, latency-tolerant); saves materializing al_e
// (12.8 MB write + 12.8 MB read).
__global__ __launch_bounds__(256) void att_edge(const int* __restrict__ ei,
                                                const float* __restrict__ a_src,
                                                const float* __restrict__ a_dst,
                                                const float* __restrict__ pack,
                                                float* __restrict__ att_out, int E) {
    int e = blockIdx.x * 256 + threadIdx.x;
    if (e >= E) return;
    int s = ei[e], d = ei[E + e];
    float4v as = *(const float4v*)(a_src + (size_t)s * 4);
    float4v ad = *(const float4v*)(a_dst + (size_t)d * 4);
    float4v mm = *(const float4v*)(pack + (size_t)d * 8);
    float4v gg = *(const float4v*)(pack + (size_t)d * 8 + 4);
    float4v o;
#pragma unroll
    for (int h = 0; h < 4; ++h)
        o[h] = fexp2(lrelu(as[h] + ad[h]) - mm[h]) * gg[h];
    *(float4v*)(att_out + (size_t)e * 4) = o;
}

// ---------------- launcher ----------------
extern "C" void kernel_launch(void* const* d_in, const int* in_sizes, int n_in,
                              void* d_out, int out_size, void* d_ws, size_t ws_size,
                              hipStream_t stream) {
    const float* x     = (const float*)d_in[0];  // fp32 [N,256]
    const int*   ei    = (const int*)d_in[1];    // int32 [2,E]
    const float* W     = (const float*)d_in[2];  // fp32 [256,256]
    const float* att_s = (const float*)d_in[3];  // fp32 [4,64]
    const float* att_d = (const float*)d_in[4];  // fp32 [4,64]

    const int N = in_sizes[0] / IN_CH;   // 50000
    const int E = in_sizes[1] / 2;       // 800000

    char* ws = (char*)d_ws;
    size_t off = 0;
    unsigned short* xh_bf = (unsigned short*)(ws + off); off += (size_t)N * HC * 2;
    unsigned short* wt    = (unsigned short*)(ws + off); off += (size_t)IN_CH * HC * 2;
    float* a_src = (float*)(ws + off); off += (size_t)N * H_HEADS * 4;
    float* a_dst = (float*)(ws + off); off += (size_t)N * H_HEADS * 4;
    float* pack  = (float*)(ws + off); off += (size_t)N * 8 * 4;
    int* rowptr  = (int*)(ws + off); off += (size_t)N * 4;
    int* cursor  = (int*)(ws + off); off += (size_t)N * 4;
    int* csr_off = (int*)(ws + off); off += (size_t)E * 4;
    float* csr_al = (float*)(ws + off); off += (size_t)E * 4 * 4 + 256; // +pad (guarded over-reads)
    int* part    = (int*)(ws + off); off += 1024 * 4;   // scan partials
    size_t zoff = off;  // zero-init region
    int* deg     = (int*)(ws + off); off += (size_t)N * 4;

    float* out     = (float*)d_out;            // [N, 256] fp32
    float* out_att = out + (size_t)N * HC;     // [E, 4]   fp32

    (void)hipMemsetAsync(ws + zoff, 0, off - zoff, stream);  // deg only

    const int NB = (N + 1023) / 1024;          // scan blocks (49 for N=50000)

    prep_w<<<256, 256, 0, stream>>>(W, wt);
    deg_count<<<(E + 255) / 256, 256, 0, stream>>>(ei, deg, E);
    gemm_xh<<<(N + 15) / 16, 256, 0, stream>>>(x, wt, att_s, att_d,
                                               xh_bf, a_src, a_dst, N);
    scan_part<<<NB, 256, 0, stream>>>(deg, part, N);
    scan_final<<<NB, 256, 0, stream>>>(deg, part, rowptr, cursor, N);
    fill_csr<<<(E + 255) / 256, 256, 0, stream>>>(ei, a_src, a_dst, cursor,
                                                  csr_off, csr_al, E);
    gat_gather<<<(N + 7) / 8, 256, 0, stream>>>(csr_off, csr_al, rowptr, deg,
                                                xh_bf, out, pack, N, E);
    att_edge<<<(E + 255) / 256, 256, 0, stream>>>(ei, a_src, a_dst, pack,
                                                  out_att, E);
}

// Round 8
// 329.900 us; speedup vs baseline: 1.0282x; 1.0282x over previous
//
#include <hip/hip_runtime.h>
#include <math.h>

// ---------------- constants (shapes fixed by the reference) ----------------
#define IN_CH   256
#define HC      256   // H*C
#define H_HEADS 4
#define NEG_SLOPE 0.2f
#define LOG2E   1.44269504088896f
#define DEFER_THR 12.0f   // base-2 defer-max threshold (2^12 = 4096, fp32-safe)
#define MINIT   -3.0e38f  // finite "-inf" so pad edges (al=-INF) are exact no-ops

typedef __attribute__((ext_vector_type(8))) short short8;
typedef __attribute__((ext_vector_type(4))) short short4v;
typedef __attribute__((ext_vector_type(4))) float float4v;

// ---------------- helpers ----------------
__device__ __forceinline__ float bf2f(unsigned short b) {
    return __uint_as_float(((unsigned)b) << 16);
}
__device__ __forceinline__ unsigned short f2bf(float f) {
    unsigned u = __float_as_uint(f);
    u += 0x7fffu + ((u >> 16) & 1u);    // round-to-nearest-even
    return (unsigned short)(u >> 16);
}
__device__ __forceinline__ float lrelu(float a) {
    return a >= 0.f ? a : NEG_SLOPE * a;
}
// base-2 exp: single v_exp_f32 (natively 2^x on gfx950).
__device__ __forceinline__ float fexp2(float a) {
    return __builtin_amdgcn_exp2f(a);
}

// ---------------- kernels ----------------

// W (fp32, [256k x 256c] row-major) -> transposed bf16 (wt[c][k])
__global__ void prep_w(const float* __restrict__ w,
                       unsigned short* __restrict__ wt) {
    int idx = blockIdx.x * 256 + threadIdx.x;   // 65536 total
    int k = idx >> 8, c = idx & 255;
    wt[(size_t)c * 256 + k] = f2bf(w[idx]);
}

// xh = x @ W. Block = 16 rows x 256 cols (4 waves = 4 heads).
// Stages fp32 x directly; bf16 hi/lo split done in-register during staging.
// Epilogue fuses node_attn; att vectors pre-scaled by LOG2E so all logits
// live in base-2 domain (consumers use exp2).
__global__ __launch_bounds__(256) void gemm_xh(const float* __restrict__ x,
                                               const unsigned short* __restrict__ wt,
                                               const float* __restrict__ att_s,
                                               const float* __restrict__ att_d,
                                               unsigned short* __restrict__ xh_bf,
                                               float* __restrict__ a_src,
                                               float* __restrict__ a_dst, int N) {
    __shared__ __attribute__((aligned(16))) unsigned char lds_a[16384];
    int tid  = threadIdx.x;
    int wave = tid >> 6;            // == head index
    int lane = tid & 63;
    int quad = lane >> 4;
    int l16  = lane & 15;
    int rb   = blockIdx.x * 16;

    // ---- stage A-tile: 512 chunks x 8 floats -> hi/lo short8 slots ----
#pragma unroll
    for (int pass = 0; pass < 2; ++pass) {
        int s  = pass * 256 + tid;              // 0..511
        int kc = s >> 4;                        // 16-B chunk index (k/8)
        int m  = s & 15;                        // row within tile
        int grow = rb + m; if (grow >= N) grow = N - 1;
        const float* gp = x + (size_t)grow * IN_CH + kc * 8;
        float4v f0 = *(const float4v*)gp;
        float4v f1 = *(const float4v*)(gp + 4);
        short8 hi, lo;
#pragma unroll
        for (int j = 0; j < 4; ++j) {
            unsigned short h0 = f2bf(f0[j]);
            hi[j] = (short)h0;
            lo[j] = (short)f2bf(f0[j] - bf2f(h0));
            unsigned short h1 = f2bf(f1[j]);
            hi[4 + j] = (short)h1;
            lo[4 + j] = (short)f2bf(f1[j] - bf2f(h1));
        }
        *(short8*)(lds_a + (size_t)s * 16) = hi;
        *(short8*)(lds_a + 8192 + (size_t)s * 16) = lo;
    }
    __syncthreads();

    // ---- K-loop: 8 x { 2 ds_read_b128 + 4 x (1 B-load + 2 MFMA) } ----
    float4v acc[4] = {};
    const unsigned short* wt_base = wt + ((size_t)wave * 64 + l16) * IN_CH;
#pragma unroll
    for (int k0 = 0; k0 < 8; ++k0) {
        int kc   = k0 * 4 + quad;
        int slot = kc * 16 + l16;
        short8 a_hi = *(const short8*)(lds_a + slot * 16);
        short8 a_lo = *(const short8*)(lds_a + 8192 + slot * 16);
#pragma unroll
        for (int ct = 0; ct < 4; ++ct) {
            short8 bh = *(const short8*)(wt_base + (size_t)ct * 16 * IN_CH
                                         + k0 * 32 + quad * 8);
            acc[ct] = __builtin_amdgcn_mfma_f32_16x16x32_bf16(a_lo, bh, acc[ct], 0, 0, 0);
            acc[ct] = __builtin_amdgcn_mfma_f32_16x16x32_bf16(a_hi, bh, acc[ct], 0, 0, 0);
        }
    }

    // ---- epilogue: xh store + fused a_src/a_dst (head = wave, base-2) ----
    int cb = wave;
    float ps[4] = {0.f, 0.f, 0.f, 0.f};
    float pd[4] = {0.f, 0.f, 0.f, 0.f};
#pragma unroll
    for (int ct = 0; ct < 4; ++ct) {
        float as_c = att_s[cb * 64 + ct * 16 + l16] * LOG2E;
        float ad_c = att_d[cb * 64 + ct * 16 + l16] * LOG2E;
#pragma unroll
        for (int r = 0; r < 4; ++r) {
            float v = acc[ct][r];
            int grow = rb + quad * 4 + r;
            if (grow < N)
                xh_bf[(size_t)grow * HC + cb * 64 + ct * 16 + l16] = f2bf(v);
            ps[r] += v * as_c;
            pd[r] += v * ad_c;
        }
    }
#pragma unroll
    for (int off = 1; off < 16; off <<= 1) {
#pragma unroll
        for (int r = 0; r < 4; ++r) {
            ps[r] += __shfl_xor(ps[r], off);
            pd[r] += __shfl_xor(pd[r], off);
        }
    }
    if (l16 == 0) {
#pragma unroll
        for (int r = 0; r < 4; ++r) {
            int grow = rb + quad * 4 + r;
            if (grow < N) {
                a_src[(size_t)grow * 4 + cb] = ps[r];
                a_dst[(size_t)grow * 4 + cb] = pd[r];
            }
        }
    }
}

// degree histogram over dst
__global__ __launch_bounds__(256) void deg_count(const int* __restrict__ ei,
                                                 int* __restrict__ deg, int E) {
    int e = blockIdx.x * 256 + threadIdx.x;
    if (e >= E) return;
    atomicAdd(deg + ei[E + e], 1);
}

// ---- device-wide exclusive scan of deg[N] -> rowptr, cursor (2 phases) ----

// phase 1: per-block sums (1024 elements / block)
__global__ __launch_bounds__(256) void scan_part(const int* __restrict__ deg,
                                                 int* __restrict__ part, int N) {
    int t = threadIdx.x;
    int base = blockIdx.x * 1024 + t * 4;
    int s = 0;
    if (base + 4 <= N) {
        int4 v = *(const int4*)(deg + base);
        s = v.x + v.y + v.z + v.w;
    } else {
#pragma unroll
        for (int j = 0; j < 4; ++j)
            if (base + j < N) s += deg[base + j];
    }
#pragma unroll
    for (int off = 1; off < 64; off <<= 1) s += __shfl_xor(s, off);
    __shared__ int ws[4];
    if ((t & 63) == 0) ws[t >> 6] = s;
    __syncthreads();
    if (t == 0) part[blockIdx.x] = ws[0] + ws[1] + ws[2] + ws[3];
}

// phase 2: block offset = sum(part[0..bid)) computed in-block (NB ~ 49),
// then local exclusive scan, write rowptr & cursor.
__global__ __launch_bounds__(256) void scan_final(const int* __restrict__ deg,
                                                  const int* __restrict__ part,
                                                  int* __restrict__ rowptr,
                                                  int* __restrict__ cursor, int N) {
    __shared__ int sm[256];
    __shared__ int wsum[4];
    int t = threadIdx.x;
    int bacc = 0;
    for (int j = t; j < blockIdx.x; j += 256) bacc += part[j];
#pragma unroll
    for (int off = 1; off < 64; off <<= 1) bacc += __shfl_xor(bacc, off);
    if ((t & 63) == 0) wsum[t >> 6] = bacc;

    int base = blockIdx.x * 1024 + t * 4;
    int v0 = 0, v1 = 0, v2 = 0, v3 = 0;
    if (base + 4 <= N) {
        int4 v = *(const int4*)(deg + base);
        v0 = v.x; v1 = v.y; v2 = v.z; v3 = v.w;
    } else {
        if (base + 0 < N) v0 = deg[base + 0];
        if (base + 1 < N) v1 = deg[base + 1];
        if (base + 2 < N) v2 = deg[base + 2];
        if (base + 3 < N) v3 = deg[base + 3];
    }
    int s = v0 + v1 + v2 + v3;
    sm[t] = s;
    __syncthreads();
    for (int off = 1; off < 256; off <<= 1) {
        int tmp = (t >= off) ? sm[t - off] : 0;
        __syncthreads();
        sm[t] += tmp;
        __syncthreads();
    }
    int boff = wsum[0] + wsum[1] + wsum[2] + wsum[3];
    int run = boff + sm[t] - s;   // exclusive prefix for this thread
    int r0 = run, r1 = r0 + v0, r2 = r1 + v1, r3 = r2 + v2;
    if (base + 4 <= N) {
        *(int4*)(rowptr + base) = (int4){r0, r1, r2, r3};
        *(int4*)(cursor + base) = (int4){r0, r1, r2, r3};
    } else {
        if (base + 0 < N) { rowptr[base + 0] = r0; cursor[base + 0] = r0; }
        if (base + 1 < N) { rowptr[base + 1] = r1; cursor[base + 1] = r1; }
        if (base + 2 < N) { rowptr[base + 2] = r2; cursor[base + 2] = r2; }
        if (base + 3 < N) { rowptr[base + 3] = r3; cursor[base + 3] = r3; }
    }
}

// fill CSR + precompute per-edge logits (base-2, lrelu applied).
// csr_off holds PRE-SHIFTED byte offsets (src * 512); csr_al slot-ordered
// so gat_gather's reads are sequential.
__global__ __launch_bounds__(256) void fill_csr(const int* __restrict__ ei,
                                                const float* __restrict__ a_src,
                                                const float* __restrict__ a_dst,
                                                int* __restrict__ cursor,
                                                int* __restrict__ csr_off,
                                                float* __restrict__ csr_al, int E) {
    int e = blockIdx.x * 256 + threadIdx.x;
    if (e >= E) return;
    int s = ei[e], d = ei[E + e];
    float4v as = *(const float4v*)(a_src + (size_t)s * 4);
    float4v ad = *(const float4v*)(a_dst + (size_t)d * 4);
    float4v al;
#pragma unroll
    for (int h = 0; h < 4; ++h) al[h] = lrelu(as[h] + ad[h]);
    int slot = atomicAdd(cursor + d, 1);
    csr_off[slot] = s << 9;   // byte offset into xh_bf (HC*2 = 512 B/row)
    *(float4v*)(csr_al + (size_t)slot * 4) = al;
}

// TWO dsts per wave (lanes 0-31 -> d0, 32-63 -> d1), 8 channels/lane.
// DEPTH-2 software pipeline: 4 xh rows in flight per wave. Pad offsets are
// PREDICATED to 0 (row 0 stays hot in L1/L2 -> ~zero HBM cost). Round 7's
// clamp-to-random-row variant cost +60 MB FETCH (245 vs 185 MB) and
// regressed 10% -- predication is the traffic filter, not overhead.
// Pad contribution zeroed by al = -INF with finite m_init.
__global__ __launch_bounds__(256) void gat_gather(const int* __restrict__ csr_off,
                                                  const float* __restrict__ csr_al,
                                                  const int* __restrict__ rowptr,
                                                  const int* __restrict__ deg,
                                                  const unsigned short* __restrict__ xh_bf,
                                                  float* __restrict__ out,
                                                  float* __restrict__ pack, int N) {
    int wave = threadIdx.x >> 6, lane = threadIdx.x & 63;
    int half = lane >> 5;           // 0 -> d0, 1 -> d1
    int l32  = lane & 31;
    int h    = l32 >> 3;            // head (8 lanes per head)
    int d    = blockIdx.x * 8 + wave * 2 + half;
    bool dv  = d < N;
    int dc   = dv ? d : N - 1;
    int start = rowptr[dc];
    int cnt   = dv ? deg[dc] : 0;
    int cntMax = max(cnt, __shfl_xor(cnt, 32));

    const char* xb = (const char*)xh_bf;
    int lboff = l32 * 16;

    float mE = MINIT, lE = 0.f, mO = MINIT, lO = 0.f;
    float accE[8] = {0.f, 0.f, 0.f, 0.f, 0.f, 0.f, 0.f, 0.f};
    float accO[8] = {0.f, 0.f, 0.f, 0.f, 0.f, 0.f, 0.f, 0.f};

#define LOFF(idx) (((idx) < cnt) ? csr_off[start + (idx)] : 0)
#define LAL(idx)  (((idx) < cnt) ? csr_al[(size_t)(start + (idx)) * 4 + h] : -INFINITY)

    // pipeline prologue: cur = edges {0,1}, nxt = edges {2,3}; offs for {4,5}
    int o4 = LOFF(4), o5 = LOFF(5);
    float alE  = LAL(0), alO  = LAL(1);
    float alE1 = LAL(2), alO1 = LAL(3);
    short8 xvE  = *(const short8*)(xb + (size_t)(unsigned)LOFF(0) + lboff);
    short8 xvO  = *(const short8*)(xb + (size_t)(unsigned)LOFF(1) + lboff);
    short8 xvE1 = *(const short8*)(xb + (size_t)(unsigned)LOFF(2) + lboff);
    short8 xvO1 = *(const short8*)(xb + (size_t)(unsigned)LOFF(3) + lboff);

#pragma unroll 2
    for (int i = 0; i < cntMax; i += 2) {
        // issue loads for edges {i+4,i+5}; fetch offsets for {i+6,i+7}
        short8 xvE2 = *(const short8*)(xb + (size_t)(unsigned)o4 + lboff);
        short8 xvO2 = *(const short8*)(xb + (size_t)(unsigned)o5 + lboff);
        int o6 = LOFF(i + 6), o7 = LOFF(i + 7);
        float alE2 = LAL(i + 4), alO2 = LAL(i + 5);

        bool ok = (alE <= mE + DEFER_THR) && (alO <= mO + DEFER_THR);
        if (__all(ok)) {
            // fast path: stale max, no rescale (pads: p = 0)
            float p = fexp2(alE - mE);
            float q = fexp2(alO - mO);
            lE += p; lO += q;
#pragma unroll
            for (int j = 0; j < 8; ++j) {
                accE[j] += p * bf2f((unsigned short)xvE[j]);
                accO[j] += q * bf2f((unsigned short)xvO[j]);
            }
        } else {
            // slow path: classic online-softmax rescale
            float mnE = fmaxf(mE, alE);
            float scE = fexp2(mE - mnE);
            float pE  = fexp2(alE - mnE);
            lE = lE * scE + pE;
            float mnO = fmaxf(mO, alO);
            float scO = fexp2(mO - mnO);
            float pO  = fexp2(alO - mnO);
            lO = lO * scO + pO;
#pragma unroll
            for (int j = 0; j < 8; ++j) {
                accE[j] = accE[j] * scE + pE * bf2f((unsigned short)xvE[j]);
                accO[j] = accO[j] * scO + pO * bf2f((unsigned short)xvO[j]);
            }
            mE = mnE; mO = mnO;
        }
        // stage shift (renamed away by unroll-2 + copy propagation)
        alE = alE1; alO = alO1; alE1 = alE2; alO1 = alO2;
        xvE = xvE1; xvO = xvO1; xvE1 = xvE2; xvO1 = xvO2;
        o4 = o6; o5 = o7;
    }
#undef LOFF
#undef LAL

    // merge E/O states (exact for stale maxes; cnt==0 -> l=0 -> o=0)
    float mm = fmaxf(mE, mO);
    float sE = fexp2(mE - mm), sO = fexp2(mO - mm);
    float l  = lE * sE + lO * sO;
    float inv = 1.f / (l + 1e-16f);
    if (dv) {
        float4v o0, o1;
#pragma unroll
        for (int j = 0; j < 4; ++j) {
            o0[j] = (accE[j] * sE + accO[j] * sO) * inv;
            o1[j] = (accE[4 + j] * sE + accO[4 + j] * sO) * inv;
        }
        float* orow = out + (size_t)d * HC + l32 * 8;
        *(float4v*)orow = o0;
        *(float4v*)(orow + 4) = o1;
        if ((l32 & 7) == 0) {
            pack[(size_t)d * 8 + h]     = mm;
            pack[(size_t)d * 8 + 4 + h] = inv;
        }
    }
}

// att[e,:] = exp2(lrelu(as+ad) - m2[d]) * inv_l[d].
// a_src/a_dst are 0.8 MB tables (L2-resident) -> random 16 B gathers are
// cheap here (edge-parallel, latency-tolerant).
__global__ __launch_bounds__(256) void att_edge(const int* __restrict__ ei,
                                                const float* __restrict__ a_src,
                                                const float* __restrict__ a_dst,
                                                const float* __restrict__ pack,
                                                float* __restrict__ att_out, int E) {
    int e = blockIdx.x * 256 + threadIdx.x;
    if (e >= E) return;
    int s = ei[e], d = ei[E + e];
    float4v as = *(const float4v*)(a_src + (size_t)s * 4);
    float4v ad = *(const float4v*)(a_dst + (size_t)d * 4);
    float4v mm = *(const float4v*)(pack + (size_t)d * 8);
    float4v gg = *(const float4v*)(pack + (size_t)d * 8 + 4);
    float4v o;
#pragma unroll
    for (int h = 0; h < 4; ++h)
        o[h] = fexp2(lrelu(as[h] + ad[h]) - mm[h]) * gg[h];
    *(float4v*)(att_out + (size_t)e * 4) = o;
}

// ---------------- launcher ----------------
extern "C" void kernel_launch(void* const* d_in, const int* in_sizes, int n_in,
                              void* d_out, int out_size, void* d_ws, size_t ws_size,
                              hipStream_t stream) {
    const float* x     = (const float*)d_in[0];  // fp32 [N,256]
    const int*   ei    = (const int*)d_in[1];    // int32 [2,E]
    const float* W     = (const float*)d_in[2];  // fp32 [256,256]
    const float* att_s = (const float*)d_in[3];  // fp32 [4,64]
    const float* att_d = (const float*)d_in[4];  // fp32 [4,64]

    const int N = in_sizes[0] / IN_CH;   // 50000
    const int E = in_sizes[1] / 2;       // 800000

    char* ws = (char*)d_ws;
    size_t off = 0;
    unsigned short* xh_bf = (unsigned short*)(ws + off); off += (size_t)N * HC * 2;
    unsigned short* wt    = (unsigned short*)(ws + off); off += (size_t)IN_CH * HC * 2;
    float* a_src = (float*)(ws + off); off += (size_t)N * H_HEADS * 4;
    float* a_dst = (float*)(ws + off); off += (size_t)N * H_HEADS * 4;
    float* pack  = (float*)(ws + off); off += (size_t)N * 8 * 4;
    int* rowptr  = (int*)(ws + off); off += (size_t)N * 4;
    int* cursor  = (int*)(ws + off); off += (size_t)N * 4;
    int* csr_off = (int*)(ws + off); off += (size_t)E * 4;
    float* csr_al = (float*)(ws + off); off += (size_t)E * 4 * 4;
    int* part    = (int*)(ws + off); off += 1024 * 4;   // scan partials
    size_t zoff = off;  // zero-init region
    int* deg     = (int*)(ws + off); off += (size_t)N * 4;

    float* out     = (float*)d_out;            // [N, 256] fp32
    float* out_att = out + (size_t)N * HC;     // [E, 4]   fp32

    (void)hipMemsetAsync(ws + zoff, 0, off - zoff, stream);  // deg only

    const int NB = (N + 1023) / 1024;          // scan blocks (49 for N=50000)

    prep_w<<<256, 256, 0, stream>>>(W, wt);
    deg_count<<<(E + 255) / 256, 256, 0, stream>>>(ei, deg, E);
    gemm_xh<<<(N + 15) / 16, 256, 0, stream>>>(x, wt, att_s, att_d,
                                               xh_bf, a_src, a_dst, N);
    scan_part<<<NB, 256, 0, stream>>>(deg, part, N);
    scan_final<<<NB, 256, 0, stream>>>(deg, part, rowptr, cursor, N);
    fill_csr<<<(E + 255) / 256, 256, 0, stream>>>(ei, a_src, a_dst, cursor,
                                                  csr_off, csr_al, E);
    gat_gather<<<(N + 7) / 8, 256, 0, stream>>>(csr_off, csr_al, rowptr, deg,
                                                xh_bf, out, pack, N);
    att_edge<<<(E + 255) / 256, 256, 0, stream>>>(ei, a_src, a_dst, pack,
                                                  out_att, E);
}